// Round 1
// baseline (352.659 us; speedup 1.0000x reference)
//
#include <hip/hip_runtime.h>
#include <math.h>

#define NN   32768
#define EE   524288
#define ETOT (EE + NN)
#define BB   32
#define NPG  1024
#define KK   512
#define INC  128
#define HID  64
#define NH   4
#define CC   256
#define SLOPE 0.2f

// ---------------- GEMM1: h[N,256] = x[N,128] @ W[128,256] ----------------
__global__ __launch_bounds__(256) void gemm1_kernel(const float* __restrict__ x,
                                                    const float* __restrict__ W,
                                                    float* __restrict__ h) {
  __shared__ float As[64][68];   // padded +4: conflict-free b32 column reads
  __shared__ float Bs[64][64];
  const int n0 = blockIdx.x * 64;
  const int c0 = blockIdx.y * 64;
  const int tid = threadIdx.x;
  const int ty = tid >> 4, tx = tid & 15;
  const int r = tid >> 4, k4 = tid & 15;
  float acc[4][4] = {};
  for (int kc = 0; kc < 2; ++kc) {
    const int k0 = kc * 64;
#pragma unroll
    for (int p = 0; p < 4; ++p) {
      int row = p * 16 + r;
      *(float4*)(&As[row][k4 * 4]) =
          *(const float4*)(x + (size_t)(n0 + row) * INC + k0 + k4 * 4);
      *(float4*)(&Bs[row][k4 * 4]) =
          *(const float4*)(W + (size_t)(k0 + row) * CC + c0 + k4 * 4);
    }
    __syncthreads();
#pragma unroll
    for (int k = 0; k < 64; ++k) {
      float4 b = *(const float4*)(&Bs[k][tx * 4]);
      float a0 = As[ty * 4 + 0][k];
      float a1 = As[ty * 4 + 1][k];
      float a2 = As[ty * 4 + 2][k];
      float a3 = As[ty * 4 + 3][k];
      acc[0][0] += a0 * b.x; acc[0][1] += a0 * b.y; acc[0][2] += a0 * b.z; acc[0][3] += a0 * b.w;
      acc[1][0] += a1 * b.x; acc[1][1] += a1 * b.y; acc[1][2] += a1 * b.z; acc[1][3] += a1 * b.w;
      acc[2][0] += a2 * b.x; acc[2][1] += a2 * b.y; acc[2][2] += a2 * b.z; acc[2][3] += a2 * b.w;
      acc[3][0] += a3 * b.x; acc[3][1] += a3 * b.y; acc[3][2] += a3 * b.z; acc[3][3] += a3 * b.w;
    }
    __syncthreads();
  }
#pragma unroll
  for (int i = 0; i < 4; ++i) {
    float4 v = make_float4(acc[i][0], acc[i][1], acc[i][2], acc[i][3]);
    *(float4*)(h + (size_t)(n0 + ty * 4 + i) * CC + c0 + tx * 4) = v;
  }
}

// ---------------- GEMM2: xl[N,64] = out[N,256] @ W_lin[256,64] + b_lin ----------------
__global__ __launch_bounds__(256) void gemm2_kernel(const float* __restrict__ A,
                                                    const float* __restrict__ Wl,
                                                    const float* __restrict__ bl,
                                                    float* __restrict__ xl) {
  __shared__ float As[64][68];
  __shared__ float Bs[64][64];
  const int n0 = blockIdx.x * 64;
  const int tid = threadIdx.x;
  const int ty = tid >> 4, tx = tid & 15;
  const int r = tid >> 4, k4 = tid & 15;
  float acc[4][4] = {};
  for (int kc = 0; kc < 4; ++kc) {
    const int k0 = kc * 64;
#pragma unroll
    for (int p = 0; p < 4; ++p) {
      int row = p * 16 + r;
      *(float4*)(&As[row][k4 * 4]) =
          *(const float4*)(A + (size_t)(n0 + row) * CC + k0 + k4 * 4);
      *(float4*)(&Bs[row][k4 * 4]) =
          *(const float4*)(Wl + (size_t)(k0 + row) * HID + k4 * 4);
    }
    __syncthreads();
#pragma unroll
    for (int k = 0; k < 64; ++k) {
      float4 b = *(const float4*)(&Bs[k][tx * 4]);
      float a0 = As[ty * 4 + 0][k];
      float a1 = As[ty * 4 + 1][k];
      float a2 = As[ty * 4 + 2][k];
      float a3 = As[ty * 4 + 3][k];
      acc[0][0] += a0 * b.x; acc[0][1] += a0 * b.y; acc[0][2] += a0 * b.z; acc[0][3] += a0 * b.w;
      acc[1][0] += a1 * b.x; acc[1][1] += a1 * b.y; acc[1][2] += a1 * b.z; acc[1][3] += a1 * b.w;
      acc[2][0] += a2 * b.x; acc[2][1] += a2 * b.y; acc[2][2] += a2 * b.z; acc[2][3] += a2 * b.w;
      acc[3][0] += a3 * b.x; acc[3][1] += a3 * b.y; acc[3][2] += a3 * b.z; acc[3][3] += a3 * b.w;
    }
    __syncthreads();
  }
  const float4 bv = *(const float4*)(bl + tx * 4);
#pragma unroll
  for (int i = 0; i < 4; ++i) {
    float4 v = make_float4(acc[i][0] + bv.x, acc[i][1] + bv.y,
                           acc[i][2] + bv.z, acc[i][3] + bv.w);
    *(float4*)(xl + (size_t)(n0 + ty * 4 + i) * HID + tx * 4) = v;
  }
}

// ---------------- per-node attention logits ----------------
__global__ __launch_bounds__(256) void al_kernel(const float* __restrict__ h,
                                                 const float* __restrict__ a_src,
                                                 const float* __restrict__ a_dst,
                                                 float* __restrict__ al_s,
                                                 float* __restrict__ al_d) {
  const int lane = threadIdx.x & 63;
  const int n = blockIdx.x * 4 + (threadIdx.x >> 6);
  const float* hr = h + (size_t)n * CC;
#pragma unroll
  for (int hd = 0; hd < NH; ++hd) {
    float hv = hr[hd * 64 + lane];
    float vs = hv * a_src[hd * 64 + lane];
    float vd = hv * a_dst[hd * 64 + lane];
#pragma unroll
    for (int off = 32; off > 0; off >>= 1) {
      vs += __shfl_down(vs, off);
      vd += __shfl_down(vd, off);
    }
    if (lane == 0) {
      al_s[n * NH + hd] = vs;
      al_d[n * NH + hd] = vd;
    }
  }
}

// ---------------- CSR build (by dst, self-loops included) ----------------
__global__ void count_kernel(const int* __restrict__ ei, int* __restrict__ cnt) {
  int e = blockIdx.x * 256 + threadIdx.x;
  if (e >= ETOT) return;
  int d = (e < EE) ? ei[EE + e] : (e - EE);
  atomicAdd(&cnt[d], 1);
}

__global__ __launch_bounds__(1024) void scan_kernel(const int* __restrict__ cnt,
                                                    int* __restrict__ row_ptr) {
  __shared__ int sums[1024];
  const int t = threadIdx.x;
  int local[32];
  int s = 0;
  const int base = t * 32;
#pragma unroll
  for (int i = 0; i < 32; ++i) { local[i] = s; s += cnt[base + i]; }
  sums[t] = s;
  __syncthreads();
  for (int off = 1; off < 1024; off <<= 1) {
    int v = (t >= off) ? sums[t - off] : 0;
    __syncthreads();
    sums[t] += v;
    __syncthreads();
  }
  const int boff = (t == 0) ? 0 : sums[t - 1];
#pragma unroll
  for (int i = 0; i < 32; ++i) row_ptr[base + i] = boff + local[i];
  if (t == 1023) row_ptr[NN] = sums[1023];
}

__global__ void scatter_kernel(const int* __restrict__ ei, const int* __restrict__ row_ptr,
                               int* __restrict__ cnt2, int* __restrict__ col) {
  int e = blockIdx.x * 256 + threadIdx.x;
  if (e >= ETOT) return;
  int s, d;
  if (e < EE) { s = ei[e]; d = ei[EE + e]; } else { s = e - EE; d = s; }
  int pos = row_ptr[d] + atomicAdd(&cnt2[d], 1);
  col[pos] = s;
}

// ---------------- softmax-weighted aggregation (wave per dst node) ----------------
__global__ __launch_bounds__(256) void agg_kernel(const float* __restrict__ h,
                                                  const float* __restrict__ al_s,
                                                  const float* __restrict__ al_d,
                                                  const int* __restrict__ row_ptr,
                                                  const int* __restrict__ col,
                                                  const float* __restrict__ b_gat,
                                                  float* __restrict__ outg) {
  const int lane = threadIdx.x & 63;
  const int n = blockIdx.x * 4 + (threadIdx.x >> 6);
  const int beg = row_ptr[n], end = row_ptr[n + 1];
  const float4 ad = *(const float4*)(al_d + n * NH);
  float acc0 = 0.f, acc1 = 0.f, acc2 = 0.f, acc3 = 0.f;
  float den0 = 0.f, den1 = 0.f, den2 = 0.f, den3 = 0.f;
  for (int j = beg; j < end; ++j) {
    const int s = col[j];
    const float4 as = *(const float4*)(al_s + s * NH);
    const float* hs = h + (size_t)s * CC;
    float e0 = as.x + ad.x; e0 = (e0 > 0.f) ? e0 : SLOPE * e0; float w0 = __expf(e0);
    float e1 = as.y + ad.y; e1 = (e1 > 0.f) ? e1 : SLOPE * e1; float w1 = __expf(e1);
    float e2 = as.z + ad.z; e2 = (e2 > 0.f) ? e2 : SLOPE * e2; float w2 = __expf(e2);
    float e3 = as.w + ad.w; e3 = (e3 > 0.f) ? e3 : SLOPE * e3; float w3 = __expf(e3);
    den0 += w0; den1 += w1; den2 += w2; den3 += w3;
    acc0 += w0 * hs[lane];
    acc1 += w1 * hs[64 + lane];
    acc2 += w2 * hs[128 + lane];
    acc3 += w3 * hs[192 + lane];
  }
  float* o = outg + (size_t)n * CC;
  o[lane]       = acc0 / den0 + b_gat[lane];
  o[64 + lane]  = acc1 / den1 + b_gat[64 + lane];
  o[128 + lane] = acc2 / den2 + b_gat[128 + lane];
  o[192 + lane] = acc3 / den3 + b_gat[192 + lane];
}

// ---------------- score = tanh(xl . p / ||p||) ----------------
__global__ __launch_bounds__(256) void score_kernel(const float* __restrict__ xl,
                                                    const float* __restrict__ p,
                                                    float* __restrict__ score) {
  const int lane = threadIdx.x & 63;
  const int n = blockIdx.x * 4 + (threadIdx.x >> 6);
  float pv = p[lane];
  float pp = pv * pv;
  float dot = xl[(size_t)n * HID + lane] * pv;
#pragma unroll
  for (int off = 32; off > 0; off >>= 1) {
    pp += __shfl_down(pp, off);
    dot += __shfl_down(dot, off);
  }
  if (lane == 0) score[n] = tanhf(dot / sqrtf(pp));
}

// ---------------- per-graph top-k via bitonic sort (desc value, asc idx tiebreak) ----------------
__global__ __launch_bounds__(1024) void topk_kernel(const float* __restrict__ score,
                                                    int* __restrict__ perm,
                                                    float* __restrict__ topv,
                                                    int* __restrict__ nmap,
                                                    float* __restrict__ out_batch) {
  __shared__ unsigned long long keys[NPG];
  const int b = blockIdx.x;
  const int t = threadIdx.x;
  {
    float sc = score[b * NPG + t];
    unsigned u = __float_as_uint(sc);
    u = (u & 0x80000000u) ? ~u : (u | 0x80000000u);  // monotone ascending encode
    u = ~u;                                           // descending
    keys[t] = ((unsigned long long)u << 32) | (unsigned)t;
  }
  __syncthreads();
  for (int k = 2; k <= NPG; k <<= 1) {
    for (int j = k >> 1; j > 0; j >>= 1) {
      int ixj = t ^ j;
      if (ixj > t) {
        unsigned long long a = keys[t], c = keys[ixj];
        bool up = ((t & k) == 0);
        if ((a > c) == up) { keys[t] = c; keys[ixj] = a; }
      }
      __syncthreads();
    }
  }
  if (t < KK) {
    unsigned long long key = keys[t];
    int idx = (int)(key & 0xFFFFFFFFull);
    int g = b * NPG + idx;
    int jj = b * KK + t;
    perm[jj] = g;
    topv[jj] = score[g];
    nmap[g] = jj;
    out_batch[jj] = (float)b;
  }
}

// ---------------- gather kept nodes, gate by score ----------------
__global__ void xp_kernel(const float* __restrict__ xl, const int* __restrict__ perm,
                          const float* __restrict__ topv, float* __restrict__ xp) {
  int idx = blockIdx.x * 256 + threadIdx.x;  // BB*KK*16 threads
  int j = idx >> 4, q = idx & 15;
  int srcn = perm[j];
  float tv = topv[j];
  float4 v = *(const float4*)(xl + (size_t)srcn * HID + q * 4);
  v.x *= tv; v.y *= tv; v.z *= tv; v.w *= tv;
  *(float4*)(xp + (size_t)j * HID + q * 4) = v;
}

// ---------------- global mean/max pool ----------------
__global__ __launch_bounds__(256) void pool_kernel(const float* __restrict__ xp,
                                                   float* __restrict__ x1) {
  __shared__ float ssum[4][64];
  __shared__ float smax[4][64];
  const int b = blockIdx.x;
  const int c = threadIdx.x & 63;
  const int g = threadIdx.x >> 6;
  const float* base = xp + (size_t)b * KK * HID;
  float s = 0.f, m = -INFINITY;
  for (int rr = g; rr < KK; rr += 4) {
    float v = base[rr * HID + c];
    s += v;
    m = fmaxf(m, v);
  }
  ssum[g][c] = s; smax[g][c] = m;
  __syncthreads();
  if (g == 0) {
    float st = ssum[0][c] + ssum[1][c] + ssum[2][c] + ssum[3][c];
    float mt = fmaxf(fmaxf(smax[0][c], smax[1][c]), fmaxf(smax[2][c], smax[3][c]));
    x1[b * 128 + c] = st * (1.0f / KK);
    x1[b * 128 + 64 + c] = mt;
  }
}

// ---------------- edge remap / filter ----------------
__global__ void edge_out_kernel(const int* __restrict__ ei, const float* __restrict__ edge,
                                const int* __restrict__ nmap,
                                float* __restrict__ out_ei, float* __restrict__ out_edge) {
  int e = blockIdx.x * 256 + threadIdx.x;
  if (e >= EE) return;
  int s = ei[e], d = ei[EE + e];
  int ns = nmap[s], nd = nmap[d];
  bool valid = (ns >= 0) && (nd >= 0);
  out_ei[e] = (float)(valid ? ns : -1);
  out_ei[EE + e] = (float)(valid ? nd : -1);
  const float4* ef = (const float4*)(edge + (size_t)e * 8);
  float4 z = make_float4(0.f, 0.f, 0.f, 0.f);
  float4 v0 = valid ? ef[0] : z;
  float4 v1 = valid ? ef[1] : z;
  float4* eo = (float4*)(out_edge + (size_t)e * 8);
  eo[0] = v0; eo[1] = v1;
}

extern "C" void kernel_launch(void* const* d_in, const int* in_sizes, int n_in,
                              void* d_out, int out_size, void* d_ws, size_t ws_size,
                              hipStream_t stream) {
  const float* x      = (const float*)d_in[0];
  const int*   ei     = (const int*)d_in[1];   // [2*E], first E src, next E dst
  const float* edge   = (const float*)d_in[2];
  // d_in[3] batch_index: implicit (contiguous blocks), unused
  const float* W      = (const float*)d_in[4];
  const float* a_src  = (const float*)d_in[5];
  const float* a_dst  = (const float*)d_in[6];
  const float* b_gat  = (const float*)d_in[7];
  const float* W_lin  = (const float*)d_in[8];
  const float* b_lin  = (const float*)d_in[9];
  const float* p_pool = (const float*)d_in[10];

  char* ws = (char*)d_ws;
  size_t off = 0;
  auto alloc = [&](size_t bytes) -> void* {
    void* p = ws + off;
    off += (bytes + 255) & ~(size_t)255;
    return p;
  };
  float* h       = (float*)alloc((size_t)NN * CC * 4);
  float* outg    = (float*)alloc((size_t)NN * CC * 4);
  float* xl      = (float*)alloc((size_t)NN * HID * 4);
  float* al_s    = (float*)alloc((size_t)NN * NH * 4);
  float* al_d    = (float*)alloc((size_t)NN * NH * 4);
  float* score   = (float*)alloc((size_t)NN * 4);
  int*   row_ptr = (int*)alloc((size_t)(NN + 1) * 4);
  int*   cnt     = (int*)alloc((size_t)NN * 4);
  int*   cnt2    = (int*)alloc((size_t)NN * 4);
  int*   col     = (int*)alloc((size_t)ETOT * 4);
  int*   nmap    = (int*)alloc((size_t)NN * 4);
  int*   perm    = (int*)alloc((size_t)BB * KK * 4);
  float* topv    = (float*)alloc((size_t)BB * KK * 4);

  float* out_xp    = (float*)d_out;                       // [B*K, 64]
  float* out_ei    = out_xp + (size_t)BB * KK * HID;      // [2, E]
  float* out_edge  = out_ei + 2 * (size_t)EE;             // [E, 8]
  float* out_batch = out_edge + (size_t)EE * 8;           // [B*K]
  float* out_x1    = out_batch + (size_t)BB * KK;         // [B, 128]

  hipMemsetAsync(cnt, 0, (size_t)NN * 4, stream);
  hipMemsetAsync(cnt2, 0, (size_t)NN * 4, stream);
  hipMemsetAsync(nmap, 0xFF, (size_t)NN * 4, stream);     // -1

  gemm1_kernel<<<dim3(NN / 64, CC / 64), 256, 0, stream>>>(x, W, h);
  al_kernel<<<NN / 4, 256, 0, stream>>>(h, a_src, a_dst, al_s, al_d);
  count_kernel<<<(ETOT + 255) / 256, 256, 0, stream>>>(ei, cnt);
  scan_kernel<<<1, 1024, 0, stream>>>(cnt, row_ptr);
  scatter_kernel<<<(ETOT + 255) / 256, 256, 0, stream>>>(ei, row_ptr, cnt2, col);
  agg_kernel<<<NN / 4, 256, 0, stream>>>(h, al_s, al_d, row_ptr, col, b_gat, outg);
  gemm2_kernel<<<NN / 64, 256, 0, stream>>>(outg, W_lin, b_lin, xl);
  score_kernel<<<NN / 4, 256, 0, stream>>>(xl, p_pool, score);
  topk_kernel<<<BB, 1024, 0, stream>>>(score, perm, topv, nmap, out_batch);
  xp_kernel<<<(BB * KK * 16) / 256, 256, 0, stream>>>(xl, perm, topv, out_xp);
  pool_kernel<<<BB, 256, 0, stream>>>(out_xp, out_x1);
  edge_out_kernel<<<(EE + 255) / 256, 256, 0, stream>>>(ei, edge, nmap, out_ei, out_edge);
}

// Round 2
// 302.486 us; speedup vs baseline: 1.1659x; 1.1659x over previous
//
#include <hip/hip_runtime.h>
#include <math.h>

#define NN   32768
#define EE   524288
#define ETOT (EE + NN)
#define BB   32
#define NPG  1024
#define KK   512
#define INC  128
#define HID  64
#define NH   4
#define CC   256
#define SLOPE 0.2f

// ---------------- GEMM1: h[N,256] = x[N,128] @ W[128,256] ----------------
// 128x64 block tile, 4x8 micro-tile. k-accumulation order identical to the
// 4x4 version (sequential k 0..127) -> bit-identical h (selection safety).
__global__ __launch_bounds__(256) void gemm1_kernel(const float* __restrict__ x,
                                                    const float* __restrict__ W,
                                                    float* __restrict__ h) {
  __shared__ float As[128][65];   // pad 65: A-read banks (r+k)%32, 8 distinct -> conflict-free
  __shared__ float Bs[64][64];
  const int n0 = blockIdx.x * 128;
  const int c0 = blockIdx.y * 64;
  const int tid = threadIdx.x;
  const int rowg = tid >> 3;      // 0..31
  const int colg = tid & 7;       // 0..7
  const int lr = tid >> 4, lq = tid & 15;
  float acc[4][8] = {};
  for (int kc = 0; kc < 2; ++kc) {
    const int k0 = kc * 64;
#pragma unroll
    for (int p = 0; p < 8; ++p) {     // A: 128 rows x 64 k
      int row = p * 16 + lr;
      float4 v = *(const float4*)(x + (size_t)(n0 + row) * INC + k0 + lq * 4);
      As[row][lq * 4 + 0] = v.x; As[row][lq * 4 + 1] = v.y;
      As[row][lq * 4 + 2] = v.z; As[row][lq * 4 + 3] = v.w;
    }
#pragma unroll
    for (int p = 0; p < 4; ++p) {     // B: 64 k x 64 c
      int krow = p * 16 + lr;
      *(float4*)(&Bs[krow][lq * 4]) =
          *(const float4*)(W + (size_t)(k0 + krow) * CC + c0 + lq * 4);
    }
    __syncthreads();
#pragma unroll
    for (int k = 0; k < 64; ++k) {
      float4 b0 = *(const float4*)(&Bs[k][colg * 8]);
      float4 b1 = *(const float4*)(&Bs[k][colg * 8 + 4]);
#pragma unroll
      for (int i = 0; i < 4; ++i) {
        float a = As[rowg * 4 + i][k];
        acc[i][0] += a * b0.x; acc[i][1] += a * b0.y;
        acc[i][2] += a * b0.z; acc[i][3] += a * b0.w;
        acc[i][4] += a * b1.x; acc[i][5] += a * b1.y;
        acc[i][6] += a * b1.z; acc[i][7] += a * b1.w;
      }
    }
    __syncthreads();
  }
#pragma unroll
  for (int i = 0; i < 4; ++i) {
    float* hp = h + (size_t)(n0 + rowg * 4 + i) * CC + c0 + colg * 8;
    *(float4*)(hp)     = make_float4(acc[i][0], acc[i][1], acc[i][2], acc[i][3]);
    *(float4*)(hp + 4) = make_float4(acc[i][4], acc[i][5], acc[i][6], acc[i][7]);
  }
}

// ---------------- GEMM2: xl[N,64] = outg[N,256] @ W_lin[256,64] + b_lin ----------------
__global__ __launch_bounds__(256) void gemm2_kernel(const float* __restrict__ A,
                                                    const float* __restrict__ Wl,
                                                    const float* __restrict__ bl,
                                                    float* __restrict__ xl) {
  __shared__ float As[128][65];
  __shared__ float Bs[64][64];
  const int n0 = blockIdx.x * 128;
  const int tid = threadIdx.x;
  const int rowg = tid >> 3, colg = tid & 7;
  const int lr = tid >> 4, lq = tid & 15;
  float acc[4][8] = {};
  for (int kc = 0; kc < 4; ++kc) {
    const int k0 = kc * 64;
#pragma unroll
    for (int p = 0; p < 8; ++p) {
      int row = p * 16 + lr;
      float4 v = *(const float4*)(A + (size_t)(n0 + row) * CC + k0 + lq * 4);
      As[row][lq * 4 + 0] = v.x; As[row][lq * 4 + 1] = v.y;
      As[row][lq * 4 + 2] = v.z; As[row][lq * 4 + 3] = v.w;
    }
#pragma unroll
    for (int p = 0; p < 4; ++p) {
      int krow = p * 16 + lr;
      *(float4*)(&Bs[krow][lq * 4]) =
          *(const float4*)(Wl + (size_t)(k0 + krow) * HID + lq * 4);
    }
    __syncthreads();
#pragma unroll
    for (int k = 0; k < 64; ++k) {
      float4 b0 = *(const float4*)(&Bs[k][colg * 8]);
      float4 b1 = *(const float4*)(&Bs[k][colg * 8 + 4]);
#pragma unroll
      for (int i = 0; i < 4; ++i) {
        float a = As[rowg * 4 + i][k];
        acc[i][0] += a * b0.x; acc[i][1] += a * b0.y;
        acc[i][2] += a * b0.z; acc[i][3] += a * b0.w;
        acc[i][4] += a * b1.x; acc[i][5] += a * b1.y;
        acc[i][6] += a * b1.z; acc[i][7] += a * b1.w;
      }
    }
    __syncthreads();
  }
  const float4 bv0 = *(const float4*)(bl + colg * 8);
  const float4 bv1 = *(const float4*)(bl + colg * 8 + 4);
#pragma unroll
  for (int i = 0; i < 4; ++i) {
    float* xp = xl + (size_t)(n0 + rowg * 4 + i) * HID + colg * 8;
    *(float4*)(xp)     = make_float4(acc[i][0] + bv0.x, acc[i][1] + bv0.y,
                                     acc[i][2] + bv0.z, acc[i][3] + bv0.w);
    *(float4*)(xp + 4) = make_float4(acc[i][4] + bv1.x, acc[i][5] + bv1.y,
                                     acc[i][6] + bv1.z, acc[i][7] + bv1.w);
  }
}

// ---------------- per-node attention logits ----------------
__global__ __launch_bounds__(256) void al_kernel(const float* __restrict__ h,
                                                 const float* __restrict__ a_src,
                                                 const float* __restrict__ a_dst,
                                                 float* __restrict__ al_s,
                                                 float* __restrict__ al_d) {
  const int lane = threadIdx.x & 63;
  const int n = blockIdx.x * 4 + (threadIdx.x >> 6);
  const float* hr = h + (size_t)n * CC;
#pragma unroll
  for (int hd = 0; hd < NH; ++hd) {
    float hv = hr[hd * 64 + lane];
    float vs = hv * a_src[hd * 64 + lane];
    float vd = hv * a_dst[hd * 64 + lane];
#pragma unroll
    for (int off = 32; off > 0; off >>= 1) {
      vs += __shfl_down(vs, off);
      vd += __shfl_down(vd, off);
    }
    if (lane == 0) {
      al_s[n * NH + hd] = vs;
      al_d[n * NH + hd] = vd;
    }
  }
}

// ---------------- CSR build (by dst, self-loops included) ----------------
__global__ void count_kernel(const int* __restrict__ ei, int* __restrict__ cnt) {
  int e = blockIdx.x * 256 + threadIdx.x;
  if (e >= ETOT) return;
  int d = (e < EE) ? ei[EE + e] : (e - EE);
  atomicAdd(&cnt[d], 1);
}

__global__ __launch_bounds__(1024) void scan_kernel(const int* __restrict__ cnt,
                                                    int* __restrict__ row_ptr) {
  __shared__ int sums[1024];
  const int t = threadIdx.x;
  int local[32];
  int s = 0;
  const int base = t * 32;
#pragma unroll
  for (int i = 0; i < 32; ++i) { local[i] = s; s += cnt[base + i]; }
  sums[t] = s;
  __syncthreads();
  for (int off = 1; off < 1024; off <<= 1) {
    int v = (t >= off) ? sums[t - off] : 0;
    __syncthreads();
    sums[t] += v;
    __syncthreads();
  }
  const int boff = (t == 0) ? 0 : sums[t - 1];
#pragma unroll
  for (int i = 0; i < 32; ++i) row_ptr[base + i] = boff + local[i];
  if (t == 1023) row_ptr[NN] = sums[1023];
}

__global__ void scatter_kernel(const int* __restrict__ ei, const int* __restrict__ row_ptr,
                               int* __restrict__ cnt2, int* __restrict__ col) {
  int e = blockIdx.x * 256 + threadIdx.x;
  if (e >= ETOT) return;
  int s, d;
  if (e < EE) { s = ei[e]; d = ei[EE + e]; } else { s = e - EE; d = s; }
  int pos = row_ptr[d] + atomicAdd(&cnt2[d], 1);
  col[pos] = s;
}

// ---------------- softmax-weighted aggregation (wave per dst node) ----------------
// XCD swizzle: blockIdx%8 -> XCD x handles graphs 4x..4x+3 (per-XCD h working
// set ~1-2 MB at a time -> fits the 4 MB per-XCD L2). Edge unroll x2 for MLP.
// Accumulation order per edge preserved (sequential) -> bit-identical outg.
__global__ __launch_bounds__(256) void agg_kernel(const float* __restrict__ h,
                                                  const float* __restrict__ al_s,
                                                  const float* __restrict__ al_d,
                                                  const int* __restrict__ row_ptr,
                                                  const int* __restrict__ col,
                                                  const float* __restrict__ b_gat,
                                                  float* __restrict__ outg) {
  const int lane = threadIdx.x & 63;
  const int xcd = blockIdx.x & 7;
  const int jb  = blockIdx.x >> 3;
  const int n = (xcd * 1024 + jb) * 4 + (threadIdx.x >> 6);
  const int beg = row_ptr[n], end = row_ptr[n + 1];
  const float4 ad = *(const float4*)(al_d + n * NH);
  float acc0 = 0.f, acc1 = 0.f, acc2 = 0.f, acc3 = 0.f;
  float den0 = 0.f, den1 = 0.f, den2 = 0.f, den3 = 0.f;
  int j = beg;
  for (; j + 1 < end; j += 2) {
    const int sA = col[j];
    const int sB = col[j + 1];
    const float4 asA = *(const float4*)(al_s + sA * NH);
    const float4 asB = *(const float4*)(al_s + sB * NH);
    const float* hsA = h + (size_t)sA * CC;
    const float* hsB = h + (size_t)sB * CC;
    float hA0 = hsA[lane], hA1 = hsA[64 + lane], hA2 = hsA[128 + lane], hA3 = hsA[192 + lane];
    float hB0 = hsB[lane], hB1 = hsB[64 + lane], hB2 = hsB[128 + lane], hB3 = hsB[192 + lane];
    float eA0 = asA.x + ad.x; eA0 = (eA0 > 0.f) ? eA0 : SLOPE * eA0; float wA0 = __expf(eA0);
    float eA1 = asA.y + ad.y; eA1 = (eA1 > 0.f) ? eA1 : SLOPE * eA1; float wA1 = __expf(eA1);
    float eA2 = asA.z + ad.z; eA2 = (eA2 > 0.f) ? eA2 : SLOPE * eA2; float wA2 = __expf(eA2);
    float eA3 = asA.w + ad.w; eA3 = (eA3 > 0.f) ? eA3 : SLOPE * eA3; float wA3 = __expf(eA3);
    float eB0 = asB.x + ad.x; eB0 = (eB0 > 0.f) ? eB0 : SLOPE * eB0; float wB0 = __expf(eB0);
    float eB1 = asB.y + ad.y; eB1 = (eB1 > 0.f) ? eB1 : SLOPE * eB1; float wB1 = __expf(eB1);
    float eB2 = asB.z + ad.z; eB2 = (eB2 > 0.f) ? eB2 : SLOPE * eB2; float wB2 = __expf(eB2);
    float eB3 = asB.w + ad.w; eB3 = (eB3 > 0.f) ? eB3 : SLOPE * eB3; float wB3 = __expf(eB3);
    den0 += wA0; den1 += wA1; den2 += wA2; den3 += wA3;
    acc0 += wA0 * hA0; acc1 += wA1 * hA1; acc2 += wA2 * hA2; acc3 += wA3 * hA3;
    den0 += wB0; den1 += wB1; den2 += wB2; den3 += wB3;
    acc0 += wB0 * hB0; acc1 += wB1 * hB1; acc2 += wB2 * hB2; acc3 += wB3 * hB3;
  }
  if (j < end) {
    const int s = col[j];
    const float4 as = *(const float4*)(al_s + s * NH);
    const float* hs = h + (size_t)s * CC;
    float e0 = as.x + ad.x; e0 = (e0 > 0.f) ? e0 : SLOPE * e0; float w0 = __expf(e0);
    float e1 = as.y + ad.y; e1 = (e1 > 0.f) ? e1 : SLOPE * e1; float w1 = __expf(e1);
    float e2 = as.z + ad.z; e2 = (e2 > 0.f) ? e2 : SLOPE * e2; float w2 = __expf(e2);
    float e3 = as.w + ad.w; e3 = (e3 > 0.f) ? e3 : SLOPE * e3; float w3 = __expf(e3);
    den0 += w0; den1 += w1; den2 += w2; den3 += w3;
    acc0 += w0 * hs[lane];
    acc1 += w1 * hs[64 + lane];
    acc2 += w2 * hs[128 + lane];
    acc3 += w3 * hs[192 + lane];
  }
  float* o = outg + (size_t)n * CC;
  o[lane]       = acc0 / den0 + b_gat[lane];
  o[64 + lane]  = acc1 / den1 + b_gat[64 + lane];
  o[128 + lane] = acc2 / den2 + b_gat[128 + lane];
  o[192 + lane] = acc3 / den3 + b_gat[192 + lane];
}

// ---------------- score = tanh(xl . p / ||p||)  (bit-identical to R1) ----------------
__global__ __launch_bounds__(256) void score_kernel(const float* __restrict__ xl,
                                                    const float* __restrict__ p,
                                                    float* __restrict__ score) {
  const int lane = threadIdx.x & 63;
  const int n = blockIdx.x * 4 + (threadIdx.x >> 6);
  float pv = p[lane];
  float pp = pv * pv;
  float dot = xl[(size_t)n * HID + lane] * pv;
#pragma unroll
  for (int off = 32; off > 0; off >>= 1) {
    pp += __shfl_down(pp, off);
    dot += __shfl_down(dot, off);
  }
  if (lane == 0) score[n] = tanhf(dot / sqrtf(pp));
}

// ---------------- per-graph top-k: hybrid bitonic (shuffle j<=32, LDS j>=64) ----------------
__device__ inline unsigned long long shflx64(unsigned long long v, int m) {
  int lo = __shfl_xor((int)(unsigned)v, m, 64);
  int hi = __shfl_xor((int)(unsigned)(v >> 32), m, 64);
  return ((unsigned long long)(unsigned)hi << 32) | (unsigned)lo;
}

__global__ __launch_bounds__(1024) void topk_kernel(const float* __restrict__ score,
                                                    int* __restrict__ perm,
                                                    float* __restrict__ topv,
                                                    int* __restrict__ nmap,
                                                    float* __restrict__ out_batch) {
  __shared__ unsigned long long keys[NPG];
  const int b = blockIdx.x;
  const int t = threadIdx.x;
  unsigned long long v;
  {
    float sc = score[b * NPG + t];
    unsigned u = __float_as_uint(sc);
    u = (u & 0x80000000u) ? ~u : (u | 0x80000000u);  // monotone ascending encode
    u = ~u;                                           // descending by score
    v = ((unsigned long long)u << 32) | (unsigned)t;  // asc idx tiebreak
  }
  for (int k = 2; k <= NPG; k <<= 1) {
    for (int j = k >> 1; j > 0; j >>= 1) {
      unsigned long long pv;
      if (j >= 64) {
        keys[t] = v;
        __syncthreads();
        pv = keys[t ^ j];
        __syncthreads();
      } else {
        pv = shflx64(v, j);
      }
      bool up = ((t & k) == 0);
      bool small_side = ((t & j) == 0);
      bool take_min = (small_side == up);
      v = take_min ? (v < pv ? v : pv) : (v > pv ? v : pv);
    }
  }
  if (t < KK) {
    int idx = (int)(v & 0xFFFFFFFFull);
    int g = b * NPG + idx;
    int jj = b * KK + t;
    perm[jj] = g;
    topv[jj] = score[g];
    nmap[g] = jj;
    out_batch[jj] = (float)b;
  }
}

// ---------------- gather kept nodes, gate by score, partial mean/max ----------------
__global__ __launch_bounds__(256) void xp_pool_kernel(const float* __restrict__ xl,
                                                      const int* __restrict__ perm,
                                                      const float* __restrict__ topv,
                                                      float* __restrict__ xp,
                                                      float* __restrict__ partials) {
  __shared__ float sred[16][68];
  __shared__ float mred[16][68];
  const int tid = threadIdx.x;
  const int r = tid >> 4, q = tid & 15;       // 16 rows x 16 col-quads
  const int j = blockIdx.x * 16 + r;          // global kept row
  const int srcn = perm[j];
  const float tv = topv[j];
  float4 val = *(const float4*)(xl + (size_t)srcn * HID + q * 4);
  val.x *= tv; val.y *= tv; val.z *= tv; val.w *= tv;
  *(float4*)(xp + (size_t)j * HID + q * 4) = val;
  sred[r][q * 4 + 0] = val.x; sred[r][q * 4 + 1] = val.y;
  sred[r][q * 4 + 2] = val.z; sred[r][q * 4 + 3] = val.w;
  mred[r][q * 4 + 0] = val.x; mred[r][q * 4 + 1] = val.y;
  mred[r][q * 4 + 2] = val.z; mred[r][q * 4 + 3] = val.w;
  __syncthreads();
  for (int s = 8; s >= 1; s >>= 1) {
    if (r < s) {
#pragma unroll
      for (int i = 0; i < 4; ++i) {
        int c = q * 4 + i;
        sred[r][c] += sred[r + s][c];
        mred[r][c] = fmaxf(mred[r][c], mred[r + s][c]);
      }
    }
    __syncthreads();
  }
  if (r == 0) {
#pragma unroll
    for (int i = 0; i < 4; ++i) {
      int c = q * 4 + i;
      partials[(size_t)blockIdx.x * 128 + c] = sred[0][c];
      partials[(size_t)blockIdx.x * 128 + 64 + c] = mred[0][c];
    }
  }
}

__global__ void pool2_kernel(const float* __restrict__ partials, float* __restrict__ x1) {
  const int b = blockIdx.x;
  const int c = threadIdx.x;   // 64
  float s = 0.f, m = -INFINITY;
  for (int pb = 0; pb < 32; ++pb) {
    const float* pp = partials + (size_t)(b * 32 + pb) * 128;
    s += pp[c];
    m = fmaxf(m, pp[64 + c]);
  }
  x1[b * 128 + c] = s * (1.0f / KK);
  x1[b * 128 + 64 + c] = m;
}

// ---------------- edge remap / filter ----------------
__global__ void edge_out_kernel(const int* __restrict__ ei, const float* __restrict__ edge,
                                const int* __restrict__ nmap,
                                float* __restrict__ out_ei, float* __restrict__ out_edge) {
  int e = blockIdx.x * 256 + threadIdx.x;
  if (e >= EE) return;
  int s = ei[e], d = ei[EE + e];
  int ns = nmap[s], nd = nmap[d];
  bool valid = (ns >= 0) && (nd >= 0);
  out_ei[e] = (float)(valid ? ns : -1);
  out_ei[EE + e] = (float)(valid ? nd : -1);
  const float4* ef = (const float4*)(edge + (size_t)e * 8);
  float4 z = make_float4(0.f, 0.f, 0.f, 0.f);
  float4 v0 = valid ? ef[0] : z;
  float4 v1 = valid ? ef[1] : z;
  float4* eo = (float4*)(out_edge + (size_t)e * 8);
  eo[0] = v0; eo[1] = v1;
}

extern "C" void kernel_launch(void* const* d_in, const int* in_sizes, int n_in,
                              void* d_out, int out_size, void* d_ws, size_t ws_size,
                              hipStream_t stream) {
  const float* x      = (const float*)d_in[0];
  const int*   ei     = (const int*)d_in[1];
  const float* edge   = (const float*)d_in[2];
  const float* W      = (const float*)d_in[4];
  const float* a_src  = (const float*)d_in[5];
  const float* a_dst  = (const float*)d_in[6];
  const float* b_gat  = (const float*)d_in[7];
  const float* W_lin  = (const float*)d_in[8];
  const float* b_lin  = (const float*)d_in[9];
  const float* p_pool = (const float*)d_in[10];

  char* ws = (char*)d_ws;
  size_t off = 0;
  auto alloc = [&](size_t bytes) -> void* {
    void* p = ws + off;
    off += (bytes + 255) & ~(size_t)255;
    return p;
  };
  float* h        = (float*)alloc((size_t)NN * CC * 4);
  float* outg     = (float*)alloc((size_t)NN * CC * 4);
  float* xl       = (float*)alloc((size_t)NN * HID * 4);
  float* al_s     = (float*)alloc((size_t)NN * NH * 4);
  float* al_d     = (float*)alloc((size_t)NN * NH * 4);
  float* score    = (float*)alloc((size_t)NN * 4);
  int*   row_ptr  = (int*)alloc((size_t)(NN + 1) * 4);
  int*   cnt      = (int*)alloc((size_t)NN * 4);
  int*   cnt2     = (int*)alloc((size_t)NN * 4);
  int*   col      = (int*)alloc((size_t)ETOT * 4);
  int*   nmap     = (int*)alloc((size_t)NN * 4);
  int*   perm     = (int*)alloc((size_t)BB * KK * 4);
  float* topv     = (float*)alloc((size_t)BB * KK * 4);
  float* partials = (float*)alloc((size_t)1024 * 128 * 4);

  float* out_xp    = (float*)d_out;
  float* out_ei    = out_xp + (size_t)BB * KK * HID;
  float* out_edge  = out_ei + 2 * (size_t)EE;
  float* out_batch = out_edge + (size_t)EE * 8;
  float* out_x1    = out_batch + (size_t)BB * KK;

  hipMemsetAsync(cnt, 0, (size_t)NN * 4, stream);
  hipMemsetAsync(cnt2, 0, (size_t)NN * 4, stream);
  hipMemsetAsync(nmap, 0xFF, (size_t)NN * 4, stream);

  gemm1_kernel<<<dim3(NN / 128, CC / 64), 256, 0, stream>>>(x, W, h);
  al_kernel<<<NN / 4, 256, 0, stream>>>(h, a_src, a_dst, al_s, al_d);
  count_kernel<<<(ETOT + 255) / 256, 256, 0, stream>>>(ei, cnt);
  scan_kernel<<<1, 1024, 0, stream>>>(cnt, row_ptr);
  scatter_kernel<<<(ETOT + 255) / 256, 256, 0, stream>>>(ei, row_ptr, cnt2, col);
  agg_kernel<<<NN / 4, 256, 0, stream>>>(h, al_s, al_d, row_ptr, col, b_gat, outg);
  gemm2_kernel<<<NN / 128, 256, 0, stream>>>(outg, W_lin, b_lin, xl);
  score_kernel<<<NN / 4, 256, 0, stream>>>(xl, p_pool, score);
  topk_kernel<<<BB, 1024, 0, stream>>>(score, perm, topv, nmap, out_batch);
  xp_pool_kernel<<<BB * KK / 16, 256, 0, stream>>>(xl, perm, topv, out_xp, partials);
  pool2_kernel<<<BB, 64, 0, stream>>>(partials, out_x1);
  edge_out_kernel<<<(EE + 255) / 256, 256, 0, stream>>>(ei, edge, nmap, out_ei, out_edge);
}